// Round 3
// baseline (930.050 us; speedup 1.0000x reference)
//
#include <hip/hip_runtime.h>

// WindowAttention for MI355X (gfx950) — round 3: GEMM-split pipeline.
//  prepN:     weight reorder (bf16) + reordered qkv bias + bias gather(-1e30 pads)
//  qkv_gemm:  M=131072(padded) x N=1536 x K=512, 128x128 m97-style tile.
//             A = X f32 reg-staged->bf16 (row-clamped pads), B = gload_lds.
//             Epilogue scatters q(scaled)/k/vt(transposed) per (win,head).
//  attn2:     barrier-free per-window attention, frags loaded global->reg,
//             swapped QK^T + shfl softmax + wave-private LDS P.
//  proj:      m97-style 128x128 GEMM (unchanged from R2, proven).
// Fallback: R2 path (attn_qkv fused) if ws too small.

typedef __bf16 bf16x8 __attribute__((ext_vector_type(8)));
typedef float f32x4 __attribute__((ext_vector_type(4)));

#define SCALE_Q 0.17677669529663687f

// ---- new-path ws layout (bytes) ----
//  [0,        1572864)    wqkv_f  bf16 [1536][512] row-major, col=(which,head,d)
//  [1572864,  2097152)    wproj_f bf16 [512][512] row-major
//  [2097152,  2359296)    bias_f  f32 [16][64][64], -1e30 pads
//  [2359296,  2365440)    qkvb_r  f32 [1536] reordered qkv bias
//  [2365440,  405018624)  qkv_ws  bf16 2048 win x 16 h x {q[64][32],k[64][32],vt[32][64]}
//  [405018624,507779072)  attnout bf16 [100352][512] compact
#define OFF_QKVWS  2365440ull
#define OFF_ATTN   405018624ull
#define WS2        507779072ull
#define WS_R2      105119744ull

__device__ __forceinline__ unsigned short f2bf(float f) {
    unsigned int u = __float_as_uint(f);
    u += 0x7FFFu + ((u >> 16) & 1u);
    return (unsigned short)(u >> 16);
}

__device__ __forceinline__ uint4 pack8(const unsigned short o[8]) {
    uint4 p;
    p.x = (unsigned)o[0] | ((unsigned)o[1] << 16);
    p.y = (unsigned)o[2] | ((unsigned)o[3] << 16);
    p.z = (unsigned)o[4] | ((unsigned)o[5] << 16);
    p.w = (unsigned)o[6] | ((unsigned)o[7] << 16);
    return p;
}

union BU8 { bf16x8 v; unsigned short s[8]; };

#define GLOAD16(g, l) __builtin_amdgcn_global_load_lds( \
    (__attribute__((address_space(1))) void*)(void*)(g), \
    (__attribute__((address_space(3))) void*)(l), 16, 0, 0)

// ================= prepN (new path) =================
__global__ void prepN_kernel(const float* __restrict__ qkv_w,
                             const float* __restrict__ qkv_b,
                             const float* __restrict__ proj_w,
                             const float* __restrict__ bias_table,
                             unsigned short* __restrict__ wqkv_f,
                             unsigned short* __restrict__ wproj_f,
                             float* __restrict__ bias_f,
                             float* __restrict__ qkvb_r) {
    int b = blockIdx.x, t = threadIdx.x;
    if (b < 384) {
        // wqkv_f[c][k] row-major, c = which*512 + head*32 + d
        int gid = b * 256 + t;              // 98304 = 1536*512/8
        int c = gid >> 6, k8 = (gid & 63) * 8;
        int which = c >> 9, head = (c >> 5) & 15, d = c & 31;
        const float* src = qkv_w + (size_t)(head * 96 + d * 3 + which) * 512 + k8;
        unsigned short o[8];
#pragma unroll
        for (int j = 0; j < 8; ++j) o[j] = f2bf(src[j]);
        *(uint4*)(wqkv_f + (size_t)c * 512 + k8) = pack8(o);
    } else if (b < 512) {
        int gid = (b - 384) * 256 + t;      // 32768 * 8 = 512*512
        const float* src = proj_w + (size_t)gid * 8;
        unsigned short o[8];
#pragma unroll
        for (int j = 0; j < 8; ++j) o[j] = f2bf(src[j]);
        *(uint4*)(wproj_f + (size_t)gid * 8) = pack8(o);
    } else if (b < 768) {
        int gid = (b - 512) * 256 + t;      // 65536
        int j = gid & 63; int i = (gid >> 6) & 63; int h = gid >> 12;
        float v = -1e30f;
        if (i < 49 && j < 49) {
            int ri = i / 7, ci = i % 7, rj = j / 7, cj = j % 7;
            int idx = (ri - rj + 6) * 13 + (ci - cj + 6);
            v = bias_table[idx * 16 + h];
        }
        bias_f[gid] = v;
    } else {
        for (int c = t; c < 1536; c += 256) {
            int which = c >> 9, head = (c >> 5) & 15, d = c & 31;
            qkvb_r[c] = qkv_b[head * 96 + d * 3 + which];
        }
    }
}

// ================= K1: qkv GEMM =================
__global__ __launch_bounds__(256, 2)
void qkv_gemm_kernel(const float* __restrict__ x,
                     const unsigned short* __restrict__ wqkv_f,
                     const float* __restrict__ qkvb_r,
                     unsigned short* __restrict__ qkv_ws) {
    __shared__ __align__(16) char smem[32768];   // A 16KB | B 16KB
    char* As = smem;
    char* Bs = smem + 16384;

    // XCD-bijective swizzle: each XCD gets contiguous mb range, nb inner.
    int i = blockIdx.x;                    // 0..12287
    int virt = (i & 7) * 1536 + (i >> 3);
    int mb = virt / 12, nb = virt % 12;
    int m0 = mb * 128, n0 = nb * 128;
    int which = n0 >> 9;                   // uniform per block

    const int tid = threadIdx.x;
    const int l = tid & 63;
    const int W = tid >> 6;
    const int lr = l & 15;
    const int lg = l >> 4;
    const int Wm = W >> 1, Wn = W & 1;

    f32x4 acc[4][4];
    const f32x4 zf = {0.f, 0.f, 0.f, 0.f};
#pragma unroll
    for (int mt = 0; mt < 4; ++mt)
#pragma unroll
        for (int nt = 0; nt < 4; ++nt) acc[mt][nt] = zf;

    // A staging source (f32 X, clamped pad rows)
    int arow = tid >> 1;                   // 0..127
    int akq = (tid & 1) * 32;              // k offset 0/32
    int awin = (mb << 1) + (arow >> 6);
    int atok = arow & 63;
    const float* asrc0 = x + ((size_t)awin * 49 + (atok < 49 ? atok : 48)) * 512 + akq;
    int aswz = (arow & 7) << 4;
    char* adst = As + arow * 128 + akq * 2;

    // B staging (gload_lds, inverse-swizzled source)
    int rsub = l >> 3, csub = l & 7;
    int cswz = (csub ^ rsub) * 16;

#pragma unroll 1
    for (int kt = 0; kt < 8; ++kt) {
        // B: [128 n][64 k] bf16
#pragma unroll
        for (int ii = 0; ii < 4; ++ii) {
            int r = ii * 32 + W * 8 + rsub;
            const char* srcB = (const char*)wqkv_f +
                ((size_t)(n0 + r) * 512 + kt * 64) * 2 + cswz;
            GLOAD16(srcB, Bs + ii * 4096 + W * 1024);
        }
        // A: load 32 f32, convert, swizzled ds_write
        {
            const float* s = asrc0 + kt * 64;
            float4 f[8];
#pragma unroll
            for (int j = 0; j < 8; ++j) f[j] = *(const float4*)(s + j * 4);
            unsigned short o[32];
#pragma unroll
            for (int j = 0; j < 8; ++j) {
                o[j*4+0] = f2bf(f[j].x); o[j*4+1] = f2bf(f[j].y);
                o[j*4+2] = f2bf(f[j].z); o[j*4+3] = f2bf(f[j].w);
            }
#pragma unroll
            for (int j = 0; j < 4; ++j)
                *(uint4*)(As + (((size_t)(adst - As)) + j * 16 ^ aswz)) = pack8(&o[j * 8]);
        }
        __syncthreads();
#pragma unroll
        for (int ks = 0; ks < 2; ++ks) {
            bf16x8 af[4], bf[4];
#pragma unroll
            for (int mt = 0; mt < 4; ++mt) {
                int row = Wm * 64 + mt * 16 + lr;
                af[mt] = *(const bf16x8*)(As + row * 128 +
                    ((ks * 64 + lg * 16) ^ ((row & 7) << 4)));
            }
#pragma unroll
            for (int nt = 0; nt < 4; ++nt) {
                int row = Wn * 64 + nt * 16 + lr;
                bf[nt] = *(const bf16x8*)(Bs + row * 128 +
                    ((ks * 64 + lg * 16) ^ ((row & 7) << 4)));
            }
#pragma unroll
            for (int mt = 0; mt < 4; ++mt)
#pragma unroll
                for (int nt = 0; nt < 4; ++nt)
                    acc[mt][nt] = __builtin_amdgcn_mfma_f32_16x16x32_bf16(
                        af[mt], bf[nt], acc[mt][nt], 0, 0, 0);
        }
        __syncthreads();
    }

    // epilogue: scatter into qkv_ws[win][head]{q[64][32],k[64][32],vt[32][64]}
    int win = (mb << 1) + Wm;              // uniform per wave
    float scale = (which == 0) ? SCALE_Q : 1.0f;
#pragma unroll
    for (int nt = 0; nt < 4; ++nt) {
        int c = Wn * 64 + nt * 16 + lr;
        int gcol = n0 + c;
        int head = (gcol >> 5) & 15, d = gcol & 31;
        float bias = qkvb_r[gcol];
        unsigned short* wh = qkv_ws + ((size_t)win * 16 + head) * 6144;
        if (which == 2) {
#pragma unroll
            for (int mt = 0; mt < 4; ++mt) {
                int tok0 = Wm * 0 + mt * 16 + lg * 4;   // tok within window
                ushort4 u;
                u.x = f2bf(acc[mt][nt][0] + bias);
                u.y = f2bf(acc[mt][nt][1] + bias);
                u.z = f2bf(acc[mt][nt][2] + bias);
                u.w = f2bf(acc[mt][nt][3] + bias);
                *(ushort4*)(wh + 4096 + d * 64 + tok0) = u;
            }
        } else {
            unsigned short* dst = wh + which * 2048;
#pragma unroll
            for (int mt = 0; mt < 4; ++mt)
#pragma unroll
                for (int r = 0; r < 4; ++r) {
                    int tok = mt * 16 + lg * 4 + r;
                    dst[tok * 32 + d] = f2bf((acc[mt][nt][r] + bias) * scale);
                }
        }
    }
}

// ================= K2: attention (barrier-free) =================
__global__ __launch_bounds__(256, 2)
void attn2_kernel(const unsigned short* __restrict__ qkv_ws,
                  const float* __restrict__ bias_f,
                  unsigned short* __restrict__ attnout) {
    __shared__ __align__(16) char P4[32768];     // 4 waves x 8KB
    const int tid = threadIdx.x;
    const int l = tid & 63;
    const int W = tid >> 6;
    const int lr = l & 15;
    const int lg = l >> 4;
    const int win = blockIdx.x;
    char* P = P4 + W * 8192;
    unsigned short* ao = attnout + (size_t)win * (49 * 512);
    const f32x4 zf = {0.f, 0.f, 0.f, 0.f};

#pragma unroll 1
    for (int hg = 0; hg < 4; ++hg) {
        int h = hg * 4 + W;
        const unsigned short* base = qkv_ws + ((size_t)win * 16 + h) * 6144;

        bf16x8 qf[4], kf[4];
#pragma unroll
        for (int i = 0; i < 4; ++i) {
            qf[i] = *(const bf16x8*)(base + (i * 16 + lr) * 32 + lg * 8);
            kf[i] = *(const bf16x8*)(base + 2048 + (i * 16 + lr) * 32 + lg * 8);
        }
        // S^T[kv][q]
        f32x4 s[4][4];
#pragma unroll
        for (int mt = 0; mt < 4; ++mt)
#pragma unroll
            for (int qt = 0; qt < 4; ++qt)
                s[mt][qt] = __builtin_amdgcn_mfma_f32_16x16x32_bf16(
                    kf[mt], qf[qt], zf, 0, 0, 0);
        // bias add (kv pads = -1e30)
#pragma unroll
        for (int qt = 0; qt < 4; ++qt) {
            int q = qt * 16 + lr;
            const float* bb = bias_f + ((size_t)h * 64 + q) * 64;
#pragma unroll
            for (int mt = 0; mt < 4; ++mt) {
                float4 b4 = *(const float4*)(bb + mt * 16 + lg * 4);
                s[mt][qt][0] += b4.x; s[mt][qt][1] += b4.y;
                s[mt][qt][2] += b4.z; s[mt][qt][3] += b4.w;
            }
        }
        // softmax per q column + P -> LDS bf16
#pragma unroll
        for (int qt = 0; qt < 4; ++qt) {
            float m = -1e30f;
#pragma unroll
            for (int mt = 0; mt < 4; ++mt)
#pragma unroll
                for (int r = 0; r < 4; ++r) m = fmaxf(m, s[mt][qt][r]);
            m = fmaxf(m, __shfl_xor(m, 16));
            m = fmaxf(m, __shfl_xor(m, 32));
            float sum = 0.f;
#pragma unroll
            for (int mt = 0; mt < 4; ++mt)
#pragma unroll
                for (int r = 0; r < 4; ++r) {
                    float p = __expf(s[mt][qt][r] - m);
                    s[mt][qt][r] = p; sum += p;
                }
            sum += __shfl_xor(sum, 16);
            sum += __shfl_xor(sum, 32);
            float inv = 1.0f / sum;
            int qrow = qt * 16 + lr;
            int sw = (qrow & 7) << 4;
#pragma unroll
            for (int mt = 0; mt < 4; ++mt) {
                uint2 uv;
                uv.x = (unsigned)f2bf(s[mt][qt][0] * inv) |
                       ((unsigned)f2bf(s[mt][qt][1] * inv) << 16);
                uv.y = (unsigned)f2bf(s[mt][qt][2] * inv) |
                       ((unsigned)f2bf(s[mt][qt][3] * inv) << 16);
                *(uint2*)(P + qrow * 128 + ((mt * 32 + lg * 8) ^ sw)) = uv;
            }
        }
        // PV
        bf16x8 vf[2][2];
#pragma unroll
        for (int ks = 0; ks < 2; ++ks)
#pragma unroll
            for (int nt = 0; nt < 2; ++nt)
                vf[ks][nt] = *(const bf16x8*)(base + 4096 +
                    (nt * 16 + lr) * 64 + ks * 32 + lg * 8);
        f32x4 o[4][2];
#pragma unroll
        for (int mt = 0; mt < 4; ++mt) {
            o[mt][0] = zf; o[mt][1] = zf;
            int q = mt * 16 + lr;
            int sw = (q & 7) << 4;
#pragma unroll
            for (int ks = 0; ks < 2; ++ks) {
                bf16x8 pf = *(const bf16x8*)(P + q * 128 + ((ks * 64 + lg * 16) ^ sw));
                o[mt][0] = __builtin_amdgcn_mfma_f32_16x16x32_bf16(pf, vf[ks][0], o[mt][0], 0, 0, 0);
                o[mt][1] = __builtin_amdgcn_mfma_f32_16x16x32_bf16(pf, vf[ks][1], o[mt][1], 0, 0, 0);
            }
        }
#pragma unroll
        for (int mt = 0; mt < 4; ++mt)
#pragma unroll
            for (int nt = 0; nt < 2; ++nt)
#pragma unroll
                for (int r = 0; r < 4; ++r) {
                    int q = mt * 16 + 4 * lg + r;
                    if (q < 49)
                        ao[q * 512 + h * 32 + nt * 16 + lr] = f2bf(o[mt][nt][r]);
                }
    }
}

// ================= K3: proj GEMM (proven R2) =================
__global__ __launch_bounds__(256, 2)
void proj_kernel(const unsigned short* __restrict__ attnout,
                 const unsigned short* __restrict__ wproj_f,
                 const float* __restrict__ proj_b,
                 float* __restrict__ out) {
    __shared__ __align__(16) char smem[32768];
    char* As = smem;
    char* Bs = smem + 16384;

    int bid = blockIdx.x;
    int c = bid >> 2;
    int cs = (c & 7) * 98 + (c >> 3);
    int m0 = cs * 128;
    int n0 = (bid & 3) * 128;

    const int tid = threadIdx.x;
    const int l = tid & 63;
    const int W = tid >> 6;
    const int lr = l & 15;
    const int lg = l >> 4;
    const int Wm = W >> 1, Wn = W & 1;

    f32x4 acc[4][4];
    const f32x4 zf = {0.f, 0.f, 0.f, 0.f};
#pragma unroll
    for (int mt = 0; mt < 4; ++mt)
#pragma unroll
        for (int nt = 0; nt < 4; ++nt) acc[mt][nt] = zf;

    int rsub = l >> 3;
    int csub = l & 7;
    int cswz = (csub ^ rsub) * 16;

#pragma unroll 1
    for (int kt = 0; kt < 8; ++kt) {
#pragma unroll
        for (int i = 0; i < 4; ++i) {
            int r = i * 32 + W * 8 + rsub;
            const char* srcA = (const char*)attnout +
                ((size_t)(m0 + r) * 512 + kt * 64) * 2 + cswz;
            GLOAD16(srcA, As + i * 4096 + W * 1024);
            const char* srcB = (const char*)wproj_f +
                ((size_t)(n0 + r) * 512 + kt * 64) * 2 + cswz;
            GLOAD16(srcB, Bs + i * 4096 + W * 1024);
        }
        __syncthreads();
#pragma unroll
        for (int ks = 0; ks < 2; ++ks) {
            bf16x8 af[4], bf[4];
#pragma unroll
            for (int mt = 0; mt < 4; ++mt) {
                int row = Wm * 64 + mt * 16 + lr;
                af[mt] = *(const bf16x8*)(As + row * 128 +
                    ((ks * 64 + lg * 16) ^ ((row & 7) << 4)));
            }
#pragma unroll
            for (int nt = 0; nt < 4; ++nt) {
                int row = Wn * 64 + nt * 16 + lr;
                bf[nt] = *(const bf16x8*)(Bs + row * 128 +
                    ((ks * 64 + lg * 16) ^ ((row & 7) << 4)));
            }
#pragma unroll
            for (int mt = 0; mt < 4; ++mt)
#pragma unroll
                for (int nt = 0; nt < 4; ++nt)
                    acc[mt][nt] = __builtin_amdgcn_mfma_f32_16x16x32_bf16(
                        af[mt], bf[nt], acc[mt][nt], 0, 0, 0);
        }
        __syncthreads();
    }
#pragma unroll
    for (int nt = 0; nt < 4; ++nt) {
        int n = n0 + Wn * 64 + nt * 16 + lr;
        float pb = proj_b[n];
#pragma unroll
        for (int mt = 0; mt < 4; ++mt) {
#pragma unroll
            for (int r = 0; r < 4; ++r) {
                int m = m0 + Wm * 64 + mt * 16 + 4 * lg + r;
                out[(size_t)m * 512 + n] = acc[mt][nt][r] + pb;
            }
        }
    }
}

// =================== FALLBACK (round-2 path, proven) ===================
__global__ void prep2_kernel(const float* __restrict__ qkv_w,
                             const float* __restrict__ proj_w,
                             const float* __restrict__ bias_table,
                             unsigned short* __restrict__ wqkv_f,
                             unsigned short* __restrict__ wproj_f,
                             float* __restrict__ bias_f) {
    int b = blockIdx.x, t = threadIdx.x;
    if (b < 384) {
        int gid = b * 256 + t;
        int l = gid & 63; int r = gid >> 6;
        int dh = r & 1; r >>= 1;
        int ks = r & 15; r >>= 4;
        int h = r & 15; int which = r >> 4;
        int d = dh * 16 + (l & 15);
        int row = h * 96 + d * 3 + which;
        int c0 = ks * 32 + (l >> 4) * 8;
        const float* src = qkv_w + row * 512 + c0;
        unsigned short o[8];
#pragma unroll
        for (int j = 0; j < 8; ++j) o[j] = f2bf(src[j]);
        *(uint4*)(wqkv_f + (size_t)gid * 8) = pack8(o);
    } else if (b < 512) {
        int gid = (b - 384) * 256 + t;
        const float* src = proj_w + (size_t)gid * 8;
        unsigned short o[8];
#pragma unroll
        for (int j = 0; j < 8; ++j) o[j] = f2bf(src[j]);
        *(uint4*)(wproj_f + (size_t)gid * 8) = pack8(o);
    } else {
        int gid = (b - 512) * 256 + t;
        int j = gid & 63; int i = (gid >> 6) & 63; int h = gid >> 12;
        float v = -1e30f;
        if (i < 49 && j < 49) {
            int ri = i / 7, ci = i % 7, rj = j / 7, cj = j % 7;
            int idx = (ri - rj + 6) * 13 + (ci - cj + 6);
            v = bias_table[idx * 16 + h];
        }
        bias_f[gid] = v;
    }
}

__global__ __launch_bounds__(256, 2)
void attn_qkv_kernel(const float* __restrict__ x,
                     const float* __restrict__ qkv_b,
                     const unsigned short* __restrict__ wqkv_f,
                     const float* __restrict__ bias_f,
                     unsigned short* __restrict__ attnout) {
    __shared__ __align__(16) char smem[81920];
    const int tid = threadIdx.x;
    const int l = tid & 63;
    const int W = tid >> 6;
    const int lr = l & 15;
    const int lg = l >> 4;
    const int win = blockIdx.x;

    bf16x8 xf[16];
    {
        int trow = 16 * W + lr; if (trow > 48) trow = 48;
        const float* xr = x + ((size_t)win * 49 + trow) * 512;
#pragma unroll
        for (int ks = 0; ks < 16; ++ks) {
            float4 a = *(const float4*)(xr + ks * 32 + lg * 8);
            float4 b = *(const float4*)(xr + ks * 32 + lg * 8 + 4);
            BU8 u;
            u.s[0] = f2bf(a.x); u.s[1] = f2bf(a.y); u.s[2] = f2bf(a.z); u.s[3] = f2bf(a.w);
            u.s[4] = f2bf(b.x); u.s[5] = f2bf(b.y); u.s[6] = f2bf(b.z); u.s[7] = f2bf(b.w);
            xf[ks] = u.v;
        }
    }

    const f32x4 zf = {0.f, 0.f, 0.f, 0.f};
    unsigned short* ao = attnout + (size_t)win * (49 * 512);

    for (int hg = 0; hg < 4; ++hg) {
        for (int h2 = 0; h2 < 4; ++h2) {
            int h = hg * 4 + h2;
            char* qk = smem + h2 * 8192;
            char* vt = smem + 32768 + h2 * 4096;
#pragma unroll 1
            for (int which = 0; which < 3; ++which) {
                f32x4 a0 = zf, a1 = zf;
                const unsigned short* bp =
                    wqkv_f + (size_t)(which * 16 + h) * 16384 + l * 8;
#pragma unroll
                for (int ks = 0; ks < 16; ++ks) {
                    bf16x8 b0 = *(const bf16x8*)(bp + ks * 1024);
                    bf16x8 b1 = *(const bf16x8*)(bp + ks * 1024 + 512);
                    a0 = __builtin_amdgcn_mfma_f32_16x16x32_bf16(xf[ks], b0, a0, 0, 0, 0);
                    a1 = __builtin_amdgcn_mfma_f32_16x16x32_bf16(xf[ks], b1, a1, 0, 0, 0);
                }
                float bias0 = qkv_b[h * 96 + lr * 3 + which];
                float bias1 = qkv_b[h * 96 + (16 + lr) * 3 + which];
                if (which == 2) {
                    int d0 = lr, d1 = 16 + lr;
#pragma unroll
                    for (int r = 0; r < 4; ++r) {
                        int t = 16 * W + 4 * lg + r;
                        *(unsigned short*)(vt + d0 * 128 + ((t * 2) ^ ((d0 & 7) << 4))) =
                            f2bf(a0[r] + bias0);
                        *(unsigned short*)(vt + d1 * 128 + ((t * 2) ^ ((d1 & 7) << 4))) =
                            f2bf(a1[r] + bias1);
                    }
                } else {
                    float sc = (which == 0) ? SCALE_Q : 1.0f;
                    int cb = which * 64;
#pragma unroll
                    for (int r = 0; r < 4; ++r) {
                        int t = 16 * W + 4 * lg + r;
                        int sw = (t & 7) << 4;
                        *(unsigned short*)(qk + t * 128 + ((cb + lr * 2) ^ sw)) =
                            f2bf((a0[r] + bias0) * sc);
                        *(unsigned short*)(qk + t * 128 + ((cb + 32 + lr * 2) ^ sw)) =
                            f2bf((a1[r] + bias1) * sc);
                    }
                }
            }
        }
        __syncthreads();
        {
            int h = hg * 4 + W;
            char* qk = smem + W * 8192;
            char* vt = smem + 32768 + W * 4096;
            char* P  = smem + 49152 + W * 8192;

            bf16x8 kf[4], qf[4];
#pragma unroll
            for (int i = 0; i < 4; ++i) {
                int row = i * 16 + lr;
                int sw = (row & 7) << 4;
                qf[i] = *(const bf16x8*)(qk + row * 128 + ((lg * 16) ^ sw));
                kf[i] = *(const bf16x8*)(qk + row * 128 + ((64 + lg * 16) ^ sw));
            }
            f32x4 s[4][4];
#pragma unroll
            for (int mt = 0; mt < 4; ++mt)
#pragma unroll
                for (int qt = 0; qt < 4; ++qt)
                    s[mt][qt] = __builtin_amdgcn_mfma_f32_16x16x32_bf16(
                        kf[mt], qf[qt], zf, 0, 0, 0);
#pragma unroll
            for (int qt = 0; qt < 4; ++qt) {
                int q = qt * 16 + lr;
                const float* bb = bias_f + ((size_t)h * 64 + q) * 64;
#pragma unroll
                for (int mt = 0; mt < 4; ++mt) {
                    float4 b4 = *(const float4*)(bb + mt * 16 + lg * 4);
                    s[mt][qt][0] += b4.x; s[mt][qt][1] += b4.y;
                    s[mt][qt][2] += b4.z; s[mt][qt][3] += b4.w;
                }
            }
#pragma unroll
            for (int qt = 0; qt < 4; ++qt) {
                float m = -1e30f;
#pragma unroll
                for (int mt = 0; mt < 4; ++mt)
#pragma unroll
                    for (int r = 0; r < 4; ++r) m = fmaxf(m, s[mt][qt][r]);
                m = fmaxf(m, __shfl_xor(m, 16));
                m = fmaxf(m, __shfl_xor(m, 32));
                float sum = 0.f;
#pragma unroll
                for (int mt = 0; mt < 4; ++mt)
#pragma unroll
                    for (int r = 0; r < 4; ++r) {
                        float p = __expf(s[mt][qt][r] - m);
                        s[mt][qt][r] = p; sum += p;
                    }
                sum += __shfl_xor(sum, 16);
                sum += __shfl_xor(sum, 32);
                float inv = 1.0f / sum;
                int qrow = qt * 16 + lr;
                int sw = (qrow & 7) << 4;
#pragma unroll
                for (int mt = 0; mt < 4; ++mt) {
                    uint2 uv;
                    uv.x = (unsigned)f2bf(s[mt][qt][0] * inv) |
                           ((unsigned)f2bf(s[mt][qt][1] * inv) << 16);
                    uv.y = (unsigned)f2bf(s[mt][qt][2] * inv) |
                           ((unsigned)f2bf(s[mt][qt][3] * inv) << 16);
                    *(uint2*)(P + qrow * 128 + ((mt * 32 + lg * 8) ^ sw)) = uv;
                }
            }
            bf16x8 vf[2][2];
#pragma unroll
            for (int ks = 0; ks < 2; ++ks)
#pragma unroll
                for (int nt = 0; nt < 2; ++nt) {
                    int d = nt * 16 + lr;
                    vf[ks][nt] = *(const bf16x8*)(vt + d * 128 +
                        ((ks * 64 + lg * 16) ^ ((d & 7) << 4)));
                }
            f32x4 o[4][2];
#pragma unroll
            for (int mt = 0; mt < 4; ++mt) {
                o[mt][0] = zf; o[mt][1] = zf;
                int q = mt * 16 + lr;
                int sw = (q & 7) << 4;
#pragma unroll
                for (int ks = 0; ks < 2; ++ks) {
                    bf16x8 pf = *(const bf16x8*)(P + q * 128 + ((ks * 64 + lg * 16) ^ sw));
                    o[mt][0] = __builtin_amdgcn_mfma_f32_16x16x32_bf16(pf, vf[ks][0], o[mt][0], 0, 0, 0);
                    o[mt][1] = __builtin_amdgcn_mfma_f32_16x16x32_bf16(pf, vf[ks][1], o[mt][1], 0, 0, 0);
                }
            }
#pragma unroll
            for (int mt = 0; mt < 4; ++mt)
#pragma unroll
                for (int nt = 0; nt < 2; ++nt)
#pragma unroll
                    for (int r = 0; r < 4; ++r) {
                        int q = mt * 16 + 4 * lg + r;
                        if (q < 49)
                            ao[q * 512 + h * 32 + nt * 16 + lr] = f2bf(o[mt][nt][r]);
                    }
        }
        __syncthreads();
    }
}

extern "C" void kernel_launch(void* const* d_in, const int* in_sizes, int n_in,
                              void* d_out, int out_size, void* d_ws, size_t ws_size,
                              hipStream_t stream) {
    const float* x          = (const float*)d_in[0];
    const float* qkv_w      = (const float*)d_in[1];
    const float* qkv_b      = (const float*)d_in[2];
    const float* proj_w     = (const float*)d_in[3];
    const float* proj_b     = (const float*)d_in[4];
    const float* bias_table = (const float*)d_in[5];

    unsigned short* wqkv_f  = (unsigned short*)d_ws;
    unsigned short* wproj_f = wqkv_f + 786432;                 // @1.5MB
    float*          bias_f  = (float*)(wproj_f + 262144);      // @2.0MB

    if (ws_size >= WS2) {
        float* qkvb_r = (float*)((char*)d_ws + 2359296);
        unsigned short* qkv_ws  = (unsigned short*)((char*)d_ws + OFF_QKVWS);
        unsigned short* attnout = (unsigned short*)((char*)d_ws + OFF_ATTN);
        hipLaunchKernelGGL(prepN_kernel, dim3(769), dim3(256), 0, stream,
                           qkv_w, qkv_b, proj_w, bias_table,
                           wqkv_f, wproj_f, bias_f, qkvb_r);
        hipLaunchKernelGGL(qkv_gemm_kernel, dim3(12288), dim3(256), 0, stream,
                           x, wqkv_f, qkvb_r, qkv_ws);
        hipLaunchKernelGGL(attn2_kernel, dim3(2048), dim3(256), 0, stream,
                           qkv_ws, bias_f, attnout);
        hipLaunchKernelGGL(proj_kernel, dim3(3136), dim3(256), 0, stream,
                           attnout, wproj_f, proj_b, (float*)d_out);
    } else if (ws_size >= WS_R2) {
        unsigned short* attnout = (unsigned short*)((char*)d_ws + 2359296);
        hipLaunchKernelGGL(prep2_kernel, dim3(768), dim3(256), 0, stream,
                           qkv_w, proj_w, bias_table, wqkv_f, wproj_f, bias_f);
        hipLaunchKernelGGL(attn_qkv_kernel, dim3(2048), dim3(256), 0, stream,
                           x, qkv_b, wqkv_f, bias_f, attnout);
        hipLaunchKernelGGL(proj_kernel, dim3(3136), dim3(256), 0, stream,
                           attnout, wproj_f, proj_b, (float*)d_out);
    }
}

// Round 4
// 624.110 us; speedup vs baseline: 1.4902x; 1.4902x over previous
//
#include <hip/hip_runtime.h>

// WindowAttention for MI355X (gfx950) — round 4.
//  prepN:    weight reorder (bf16), bias gather (-1e30 pads), qkv-bias reorder,
//            x -> bf16 pre-swizzled compact copy (xs).
//  qkv_gemm: M=100352 x N=1536 x K=512, 128x128 tile, BOTH operands via
//            global_load_lds (proj-identical core). Epilogue scatters
//            q(scaled)/k/vt per (win,head) with exact div-49 row mapping.
//  attn2:    barrier-free per-window attention (unchanged, proven).
//  proj:     m97-style 128x128 GEMM (unchanged, proven).
// attnout overlays xs (xs dead after qkv_gemm) -> ws requirement unchanged.

typedef __bf16 bf16x8 __attribute__((ext_vector_type(8)));
typedef float f32x4 __attribute__((ext_vector_type(4)));

#define SCALE_Q 0.17677669529663687f

// ---- ws layout (bytes) ----
//  [0,        1572864)    wqkv_f  bf16 [1536][512] row-major, col=(which,head,d)
//  [1572864,  2097152)    wproj_f bf16 [512][512] row-major
//  [2097152,  2359296)    bias_f  f32 [16][64][64], -1e30 pads
//  [2359296,  2365440)    qkvb_r  f32 [1536]
//  [2365440,  105125888)  xs      bf16 [100352][512] pre-swizzled   (phase 1)
//                         attnout bf16 [100352][512] compact        (phase 2, overlay)
//  [105125888,507779072)  qkv_ws  bf16 2048 win x 16 h x {q[64][32],k[64][32],vt[32][64]}
#define OFF_XS     2365440ull
#define OFF_QKVWS  105125888ull
#define WS2        507779072ull
#define WS_R2      105119744ull

__device__ __forceinline__ unsigned short f2bf(float f) {
    unsigned int u = __float_as_uint(f);
    u += 0x7FFFu + ((u >> 16) & 1u);
    return (unsigned short)(u >> 16);
}

__device__ __forceinline__ uint4 pack8(const unsigned short o[8]) {
    uint4 p;
    p.x = (unsigned)o[0] | ((unsigned)o[1] << 16);
    p.y = (unsigned)o[2] | ((unsigned)o[3] << 16);
    p.z = (unsigned)o[4] | ((unsigned)o[5] << 16);
    p.w = (unsigned)o[6] | ((unsigned)o[7] << 16);
    return p;
}

union BU8 { bf16x8 v; unsigned short s[8]; };

#define GLOAD16(g, l) __builtin_amdgcn_global_load_lds( \
    (__attribute__((address_space(1))) void*)(void*)(g), \
    (__attribute__((address_space(3))) void*)(l), 16, 0, 0)

// exact win = row/49, tok = row%49 for row < 4.29e8
__device__ __forceinline__ void div49(int row, int& win, int& tok) {
    win = (int)(((unsigned long long)(unsigned)row * 87652394ull) >> 32);
    tok = row - win * 49;
}

// ================= prepN =================
__global__ void prepN_kernel(const float* __restrict__ x,
                             const float* __restrict__ qkv_w,
                             const float* __restrict__ qkv_b,
                             const float* __restrict__ proj_w,
                             const float* __restrict__ bias_table,
                             unsigned short* __restrict__ wqkv_f,
                             unsigned short* __restrict__ wproj_f,
                             float* __restrict__ bias_f,
                             float* __restrict__ qkvb_r,
                             unsigned short* __restrict__ xs) {
    int b = blockIdx.x, t = threadIdx.x;
    if (b < 384) {
        // wqkv_f[c][k] row-major, c = which*512 + head*32 + d
        int gid = b * 256 + t;              // 98304 = 1536*512/8
        int c = gid >> 6, k8 = (gid & 63) * 8;
        int which = c >> 9, head = (c >> 5) & 15, d = c & 31;
        const float* src = qkv_w + (size_t)(head * 96 + d * 3 + which) * 512 + k8;
        unsigned short o[8];
#pragma unroll
        for (int j = 0; j < 8; ++j) o[j] = f2bf(src[j]);
        *(uint4*)(wqkv_f + (size_t)c * 512 + k8) = pack8(o);
    } else if (b < 512) {
        int gid = (b - 384) * 256 + t;      // 32768 * 8 = 512*512
        const float* src = proj_w + (size_t)gid * 8;
        unsigned short o[8];
#pragma unroll
        for (int j = 0; j < 8; ++j) o[j] = f2bf(src[j]);
        *(uint4*)(wproj_f + (size_t)gid * 8) = pack8(o);
    } else if (b < 768) {
        int gid = (b - 512) * 256 + t;      // 65536
        int j = gid & 63; int i = (gid >> 6) & 63; int h = gid >> 12;
        float v = -1e30f;
        if (i < 49 && j < 49) {
            int ri = i / 7, ci = i % 7, rj = j / 7, cj = j % 7;
            int idx = (ri - rj + 6) * 13 + (ci - cj + 6);
            v = bias_table[idx * 16 + h];
        }
        bias_f[gid] = v;
    } else if (b == 768) {
        for (int c = t; c < 1536; c += 256) {
            int which = c >> 9, head = (c >> 5) & 15, d = c & 31;
            qkvb_r[c] = qkv_b[head * 96 + d * 3 + which];
        }
    } else {
        // x -> bf16, pre-swizzled: xs[row][kt*64 + c*8 ..] = x[row][kt*64 + (c^(row&7))*8 ..]
        int gid = (b - 769) * 256 + t;      // < 802816 = 100352*8
        int row = gid >> 3, kt = gid & 7;
        int sw = row & 7;
        const float* src = x + (size_t)row * 512 + kt * 64;
        unsigned short* dst = xs + (size_t)row * 512 + kt * 64;
#pragma unroll
        for (int c = 0; c < 8; ++c) {
            int cs = (c ^ sw) * 8;
            float4 a = *(const float4*)(src + cs);
            float4 bb = *(const float4*)(src + cs + 4);
            unsigned short o[8];
            o[0] = f2bf(a.x); o[1] = f2bf(a.y); o[2] = f2bf(a.z); o[3] = f2bf(a.w);
            o[4] = f2bf(bb.x); o[5] = f2bf(bb.y); o[6] = f2bf(bb.z); o[7] = f2bf(bb.w);
            *(uint4*)(dst + c * 8) = pack8(o);
        }
    }
}

// ================= K1: qkv GEMM (proj-identical core) =================
__global__ __launch_bounds__(256, 2)
void qkv_gemm_kernel(const unsigned short* __restrict__ xs,
                     const unsigned short* __restrict__ wqkv_f,
                     const float* __restrict__ qkvb_r,
                     unsigned short* __restrict__ qkv_ws) {
    __shared__ __align__(16) char smem[32768];   // A 16KB | B 16KB
    char* As = smem;
    char* Bs = smem + 16384;

    // XCD-bijective swizzle; 12 consecutive virt share mb -> A L2-local per XCD
    int i = blockIdx.x;                    // 0..9407 = 8*1176
    int virt = (i & 7) * 1176 + (i >> 3);
    int mb = virt / 12, nb = virt % 12;
    int m0 = mb * 128, n0 = nb * 128;
    int which = n0 >> 9;                   // uniform per block

    const int tid = threadIdx.x;
    const int l = tid & 63;
    const int W = tid >> 6;
    const int lr = l & 15;
    const int lg = l >> 4;
    const int Wm = W >> 1, Wn = W & 1;

    f32x4 acc[4][4];
    const f32x4 zf = {0.f, 0.f, 0.f, 0.f};
#pragma unroll
    for (int mt = 0; mt < 4; ++mt)
#pragma unroll
        for (int nt = 0; nt < 4; ++nt) acc[mt][nt] = zf;

    int rsub = l >> 3, csub = l & 7;
    int cswz = (csub ^ rsub) * 16;         // B runtime inverse-swizzle
    int clin = csub * 16;                  // A linear (xs pre-swizzled)

#pragma unroll 1
    for (int kt = 0; kt < 8; ++kt) {
#pragma unroll
        for (int ii = 0; ii < 4; ++ii) {
            int r = ii * 32 + W * 8 + rsub;
            const char* srcA = (const char*)xs +
                ((size_t)(m0 + r) * 512 + kt * 64) * 2 + clin;
            GLOAD16(srcA, As + ii * 4096 + W * 1024);
            const char* srcB = (const char*)wqkv_f +
                ((size_t)(n0 + r) * 512 + kt * 64) * 2 + cswz;
            GLOAD16(srcB, Bs + ii * 4096 + W * 1024);
        }
        __syncthreads();
#pragma unroll
        for (int ks = 0; ks < 2; ++ks) {
            bf16x8 af[4], bf[4];
#pragma unroll
            for (int mt = 0; mt < 4; ++mt) {
                int row = Wm * 64 + mt * 16 + lr;
                af[mt] = *(const bf16x8*)(As + row * 128 +
                    ((ks * 64 + lg * 16) ^ ((row & 7) << 4)));
            }
#pragma unroll
            for (int nt = 0; nt < 4; ++nt) {
                int row = Wn * 64 + nt * 16 + lr;
                bf[nt] = *(const bf16x8*)(Bs + row * 128 +
                    ((ks * 64 + lg * 16) ^ ((row & 7) << 4)));
            }
#pragma unroll
            for (int mt = 0; mt < 4; ++mt)
#pragma unroll
                for (int nt = 0; nt < 4; ++nt)
                    acc[mt][nt] = __builtin_amdgcn_mfma_f32_16x16x32_bf16(
                        af[mt], bf[nt], acc[mt][nt], 0, 0, 0);
        }
        __syncthreads();
    }

    // epilogue: scatter into qkv_ws[win][head]{q[64][32],k[64][32],vt[32][64]}
    float scale = (which == 0) ? SCALE_Q : 1.0f;
#pragma unroll
    for (int mt = 0; mt < 4; ++mt) {
        int row0 = m0 + Wm * 64 + mt * 16 + 4 * lg;
        int w[4], tk[4];
#pragma unroll
        for (int r = 0; r < 4; ++r) div49(row0 + r, w[r], tk[r]);
#pragma unroll
        for (int nt = 0; nt < 4; ++nt) {
            int gcol = n0 + Wn * 64 + nt * 16 + lr;
            int head = (gcol >> 5) & 15, d = gcol & 31;
            float bias = qkvb_r[gcol];
            if (which == 2) {
#pragma unroll
                for (int r = 0; r < 4; ++r)
                    qkv_ws[((size_t)w[r] * 16 + head) * 6144 + 4096 + d * 64 + tk[r]] =
                        f2bf(acc[mt][nt][r] + bias);
            } else {
                size_t wb = (size_t)which * 2048;
#pragma unroll
                for (int r = 0; r < 4; ++r)
                    qkv_ws[((size_t)w[r] * 16 + head) * 6144 + wb + tk[r] * 32 + d] =
                        f2bf((acc[mt][nt][r] + bias) * scale);
            }
        }
    }
}

// ================= K2: attention (unchanged, proven) =================
__global__ __launch_bounds__(256, 2)
void attn2_kernel(const unsigned short* __restrict__ qkv_ws,
                  const float* __restrict__ bias_f,
                  unsigned short* __restrict__ attnout) {
    __shared__ __align__(16) char P4[32768];     // 4 waves x 8KB
    const int tid = threadIdx.x;
    const int l = tid & 63;
    const int W = tid >> 6;
    const int lr = l & 15;
    const int lg = l >> 4;
    const int win = blockIdx.x;
    char* P = P4 + W * 8192;
    unsigned short* ao = attnout + (size_t)win * (49 * 512);
    const f32x4 zf = {0.f, 0.f, 0.f, 0.f};

#pragma unroll 1
    for (int hg = 0; hg < 4; ++hg) {
        int h = hg * 4 + W;
        const unsigned short* base = qkv_ws + ((size_t)win * 16 + h) * 6144;

        bf16x8 qf[4], kf[4];
#pragma unroll
        for (int i = 0; i < 4; ++i) {
            qf[i] = *(const bf16x8*)(base + (i * 16 + lr) * 32 + lg * 8);
            kf[i] = *(const bf16x8*)(base + 2048 + (i * 16 + lr) * 32 + lg * 8);
        }
        f32x4 s[4][4];
#pragma unroll
        for (int mt = 0; mt < 4; ++mt)
#pragma unroll
            for (int qt = 0; qt < 4; ++qt)
                s[mt][qt] = __builtin_amdgcn_mfma_f32_16x16x32_bf16(
                    kf[mt], qf[qt], zf, 0, 0, 0);
#pragma unroll
        for (int qt = 0; qt < 4; ++qt) {
            int q = qt * 16 + lr;
            const float* bb = bias_f + ((size_t)h * 64 + q) * 64;
#pragma unroll
            for (int mt = 0; mt < 4; ++mt) {
                float4 b4 = *(const float4*)(bb + mt * 16 + lg * 4);
                s[mt][qt][0] += b4.x; s[mt][qt][1] += b4.y;
                s[mt][qt][2] += b4.z; s[mt][qt][3] += b4.w;
            }
        }
#pragma unroll
        for (int qt = 0; qt < 4; ++qt) {
            float m = -1e30f;
#pragma unroll
            for (int mt = 0; mt < 4; ++mt)
#pragma unroll
                for (int r = 0; r < 4; ++r) m = fmaxf(m, s[mt][qt][r]);
            m = fmaxf(m, __shfl_xor(m, 16));
            m = fmaxf(m, __shfl_xor(m, 32));
            float sum = 0.f;
#pragma unroll
            for (int mt = 0; mt < 4; ++mt)
#pragma unroll
                for (int r = 0; r < 4; ++r) {
                    float p = __expf(s[mt][qt][r] - m);
                    s[mt][qt][r] = p; sum += p;
                }
            sum += __shfl_xor(sum, 16);
            sum += __shfl_xor(sum, 32);
            float inv = 1.0f / sum;
            int qrow = qt * 16 + lr;
            int sw = (qrow & 7) << 4;
#pragma unroll
            for (int mt = 0; mt < 4; ++mt) {
                uint2 uv;
                uv.x = (unsigned)f2bf(s[mt][qt][0] * inv) |
                       ((unsigned)f2bf(s[mt][qt][1] * inv) << 16);
                uv.y = (unsigned)f2bf(s[mt][qt][2] * inv) |
                       ((unsigned)f2bf(s[mt][qt][3] * inv) << 16);
                *(uint2*)(P + qrow * 128 + ((mt * 32 + lg * 8) ^ sw)) = uv;
            }
        }
        bf16x8 vf[2][2];
#pragma unroll
        for (int ks = 0; ks < 2; ++ks)
#pragma unroll
            for (int nt = 0; nt < 2; ++nt)
                vf[ks][nt] = *(const bf16x8*)(base + 4096 +
                    (nt * 16 + lr) * 64 + ks * 32 + lg * 8);
        f32x4 o[4][2];
#pragma unroll
        for (int mt = 0; mt < 4; ++mt) {
            o[mt][0] = zf; o[mt][1] = zf;
            int q = mt * 16 + lr;
            int sw = (q & 7) << 4;
#pragma unroll
            for (int ks = 0; ks < 2; ++ks) {
                bf16x8 pf = *(const bf16x8*)(P + q * 128 + ((ks * 64 + lg * 16) ^ sw));
                o[mt][0] = __builtin_amdgcn_mfma_f32_16x16x32_bf16(pf, vf[ks][0], o[mt][0], 0, 0, 0);
                o[mt][1] = __builtin_amdgcn_mfma_f32_16x16x32_bf16(pf, vf[ks][1], o[mt][1], 0, 0, 0);
            }
        }
#pragma unroll
        for (int mt = 0; mt < 4; ++mt)
#pragma unroll
            for (int nt = 0; nt < 2; ++nt)
#pragma unroll
                for (int r = 0; r < 4; ++r) {
                    int q = mt * 16 + 4 * lg + r;
                    if (q < 49)
                        ao[q * 512 + h * 32 + nt * 16 + lr] = f2bf(o[mt][nt][r]);
                }
    }
}

// ================= K3: proj GEMM (unchanged, proven) =================
__global__ __launch_bounds__(256, 2)
void proj_kernel(const unsigned short* __restrict__ attnout,
                 const unsigned short* __restrict__ wproj_f,
                 const float* __restrict__ proj_b,
                 float* __restrict__ out) {
    __shared__ __align__(16) char smem[32768];
    char* As = smem;
    char* Bs = smem + 16384;

    int bid = blockIdx.x;
    int c = bid >> 2;
    int cs = (c & 7) * 98 + (c >> 3);
    int m0 = cs * 128;
    int n0 = (bid & 3) * 128;

    const int tid = threadIdx.x;
    const int l = tid & 63;
    const int W = tid >> 6;
    const int lr = l & 15;
    const int lg = l >> 4;
    const int Wm = W >> 1, Wn = W & 1;

    f32x4 acc[4][4];
    const f32x4 zf = {0.f, 0.f, 0.f, 0.f};
#pragma unroll
    for (int mt = 0; mt < 4; ++mt)
#pragma unroll
        for (int nt = 0; nt < 4; ++nt) acc[mt][nt] = zf;

    int rsub = l >> 3;
    int csub = l & 7;
    int cswz = (csub ^ rsub) * 16;

#pragma unroll 1
    for (int kt = 0; kt < 8; ++kt) {
#pragma unroll
        for (int i = 0; i < 4; ++i) {
            int r = i * 32 + W * 8 + rsub;
            const char* srcA = (const char*)attnout +
                ((size_t)(m0 + r) * 512 + kt * 64) * 2 + cswz;
            GLOAD16(srcA, As + i * 4096 + W * 1024);
            const char* srcB = (const char*)wproj_f +
                ((size_t)(n0 + r) * 512 + kt * 64) * 2 + cswz;
            GLOAD16(srcB, Bs + i * 4096 + W * 1024);
        }
        __syncthreads();
#pragma unroll
        for (int ks = 0; ks < 2; ++ks) {
            bf16x8 af[4], bf[4];
#pragma unroll
            for (int mt = 0; mt < 4; ++mt) {
                int row = Wm * 64 + mt * 16 + lr;
                af[mt] = *(const bf16x8*)(As + row * 128 +
                    ((ks * 64 + lg * 16) ^ ((row & 7) << 4)));
            }
#pragma unroll
            for (int nt = 0; nt < 4; ++nt) {
                int row = Wn * 64 + nt * 16 + lr;
                bf[nt] = *(const bf16x8*)(Bs + row * 128 +
                    ((ks * 64 + lg * 16) ^ ((row & 7) << 4)));
            }
#pragma unroll
            for (int mt = 0; mt < 4; ++mt)
#pragma unroll
                for (int nt = 0; nt < 4; ++nt)
                    acc[mt][nt] = __builtin_amdgcn_mfma_f32_16x16x32_bf16(
                        af[mt], bf[nt], acc[mt][nt], 0, 0, 0);
        }
        __syncthreads();
    }
#pragma unroll
    for (int nt = 0; nt < 4; ++nt) {
        int n = n0 + Wn * 64 + nt * 16 + lr;
        float pb = proj_b[n];
#pragma unroll
        for (int mt = 0; mt < 4; ++mt) {
#pragma unroll
            for (int r = 0; r < 4; ++r) {
                int m = m0 + Wm * 64 + mt * 16 + 4 * lg + r;
                out[(size_t)m * 512 + n] = acc[mt][nt][r] + pb;
            }
        }
    }
}

// =================== FALLBACK (round-2 path, proven) ===================
__global__ void prep2_kernel(const float* __restrict__ qkv_w,
                             const float* __restrict__ proj_w,
                             const float* __restrict__ bias_table,
                             unsigned short* __restrict__ wqkv_f,
                             unsigned short* __restrict__ wproj_f,
                             float* __restrict__ bias_f) {
    int b = blockIdx.x, t = threadIdx.x;
    if (b < 384) {
        int gid = b * 256 + t;
        int l = gid & 63; int r = gid >> 6;
        int dh = r & 1; r >>= 1;
        int ks = r & 15; r >>= 4;
        int h = r & 15; int which = r >> 4;
        int d = dh * 16 + (l & 15);
        int row = h * 96 + d * 3 + which;
        int c0 = ks * 32 + (l >> 4) * 8;
        const float* src = qkv_w + row * 512 + c0;
        unsigned short o[8];
#pragma unroll
        for (int j = 0; j < 8; ++j) o[j] = f2bf(src[j]);
        *(uint4*)(wqkv_f + (size_t)gid * 8) = pack8(o);
    } else if (b < 512) {
        int gid = (b - 384) * 256 + t;
        const float* src = proj_w + (size_t)gid * 8;
        unsigned short o[8];
#pragma unroll
        for (int j = 0; j < 8; ++j) o[j] = f2bf(src[j]);
        *(uint4*)(wproj_f + (size_t)gid * 8) = pack8(o);
    } else {
        int gid = (b - 512) * 256 + t;
        int j = gid & 63; int i = (gid >> 6) & 63; int h = gid >> 12;
        float v = -1e30f;
        if (i < 49 && j < 49) {
            int ri = i / 7, ci = i % 7, rj = j / 7, cj = j % 7;
            int idx = (ri - rj + 6) * 13 + (ci - cj + 6);
            v = bias_table[idx * 16 + h];
        }
        bias_f[gid] = v;
    }
}

__global__ __launch_bounds__(256, 2)
void attn_qkv_kernel(const float* __restrict__ x,
                     const float* __restrict__ qkv_b,
                     const unsigned short* __restrict__ wqkv_f,
                     const float* __restrict__ bias_f,
                     unsigned short* __restrict__ attnout) {
    __shared__ __align__(16) char smem[81920];
    const int tid = threadIdx.x;
    const int l = tid & 63;
    const int W = tid >> 6;
    const int lr = l & 15;
    const int lg = l >> 4;
    const int win = blockIdx.x;

    bf16x8 xf[16];
    {
        int trow = 16 * W + lr; if (trow > 48) trow = 48;
        const float* xr = x + ((size_t)win * 49 + trow) * 512;
#pragma unroll
        for (int ks = 0; ks < 16; ++ks) {
            float4 a = *(const float4*)(xr + ks * 32 + lg * 8);
            float4 b = *(const float4*)(xr + ks * 32 + lg * 8 + 4);
            BU8 u;
            u.s[0] = f2bf(a.x); u.s[1] = f2bf(a.y); u.s[2] = f2bf(a.z); u.s[3] = f2bf(a.w);
            u.s[4] = f2bf(b.x); u.s[5] = f2bf(b.y); u.s[6] = f2bf(b.z); u.s[7] = f2bf(b.w);
            xf[ks] = u.v;
        }
    }

    const f32x4 zf = {0.f, 0.f, 0.f, 0.f};
    unsigned short* ao = attnout + (size_t)win * (49 * 512);

    for (int hg = 0; hg < 4; ++hg) {
        for (int h2 = 0; h2 < 4; ++h2) {
            int h = hg * 4 + h2;
            char* qk = smem + h2 * 8192;
            char* vt = smem + 32768 + h2 * 4096;
#pragma unroll 1
            for (int which = 0; which < 3; ++which) {
                f32x4 a0 = zf, a1 = zf;
                const unsigned short* bp =
                    wqkv_f + (size_t)(which * 16 + h) * 16384 + l * 8;
#pragma unroll
                for (int ks = 0; ks < 16; ++ks) {
                    bf16x8 b0 = *(const bf16x8*)(bp + ks * 1024);
                    bf16x8 b1 = *(const bf16x8*)(bp + ks * 1024 + 512);
                    a0 = __builtin_amdgcn_mfma_f32_16x16x32_bf16(xf[ks], b0, a0, 0, 0, 0);
                    a1 = __builtin_amdgcn_mfma_f32_16x16x32_bf16(xf[ks], b1, a1, 0, 0, 0);
                }
                float bias0 = qkv_b[h * 96 + lr * 3 + which];
                float bias1 = qkv_b[h * 96 + (16 + lr) * 3 + which];
                if (which == 2) {
                    int d0 = lr, d1 = 16 + lr;
#pragma unroll
                    for (int r = 0; r < 4; ++r) {
                        int t = 16 * W + 4 * lg + r;
                        *(unsigned short*)(vt + d0 * 128 + ((t * 2) ^ ((d0 & 7) << 4))) =
                            f2bf(a0[r] + bias0);
                        *(unsigned short*)(vt + d1 * 128 + ((t * 2) ^ ((d1 & 7) << 4))) =
                            f2bf(a1[r] + bias1);
                    }
                } else {
                    float sc = (which == 0) ? SCALE_Q : 1.0f;
                    int cb = which * 64;
#pragma unroll
                    for (int r = 0; r < 4; ++r) {
                        int t = 16 * W + 4 * lg + r;
                        int sw = (t & 7) << 4;
                        *(unsigned short*)(qk + t * 128 + ((cb + lr * 2) ^ sw)) =
                            f2bf((a0[r] + bias0) * sc);
                        *(unsigned short*)(qk + t * 128 + ((cb + 32 + lr * 2) ^ sw)) =
                            f2bf((a1[r] + bias1) * sc);
                    }
                }
            }
        }
        __syncthreads();
        {
            int h = hg * 4 + W;
            char* qk = smem + W * 8192;
            char* vt = smem + 32768 + W * 4096;
            char* P  = smem + 49152 + W * 8192;

            bf16x8 kf[4], qf[4];
#pragma unroll
            for (int i = 0; i < 4; ++i) {
                int row = i * 16 + lr;
                int sw = (row & 7) << 4;
                qf[i] = *(const bf16x8*)(qk + row * 128 + ((lg * 16) ^ sw));
                kf[i] = *(const bf16x8*)(qk + row * 128 + ((64 + lg * 16) ^ sw));
            }
            f32x4 s[4][4];
#pragma unroll
            for (int mt = 0; mt < 4; ++mt)
#pragma unroll
                for (int qt = 0; qt < 4; ++qt)
                    s[mt][qt] = __builtin_amdgcn_mfma_f32_16x16x32_bf16(
                        kf[mt], qf[qt], zf, 0, 0, 0);
#pragma unroll
            for (int qt = 0; qt < 4; ++qt) {
                int q = qt * 16 + lr;
                const float* bb = bias_f + ((size_t)h * 64 + q) * 64;
#pragma unroll
                for (int mt = 0; mt < 4; ++mt) {
                    float4 b4 = *(const float4*)(bb + mt * 16 + lg * 4);
                    s[mt][qt][0] += b4.x; s[mt][qt][1] += b4.y;
                    s[mt][qt][2] += b4.z; s[mt][qt][3] += b4.w;
                }
            }
#pragma unroll
            for (int qt = 0; qt < 4; ++qt) {
                float m = -1e30f;
#pragma unroll
                for (int mt = 0; mt < 4; ++mt)
#pragma unroll
                    for (int r = 0; r < 4; ++r) m = fmaxf(m, s[mt][qt][r]);
                m = fmaxf(m, __shfl_xor(m, 16));
                m = fmaxf(m, __shfl_xor(m, 32));
                float sum = 0.f;
#pragma unroll
                for (int mt = 0; mt < 4; ++mt)
#pragma unroll
                    for (int r = 0; r < 4; ++r) {
                        float p = __expf(s[mt][qt][r] - m);
                        s[mt][qt][r] = p; sum += p;
                    }
                sum += __shfl_xor(sum, 16);
                sum += __shfl_xor(sum, 32);
                float inv = 1.0f / sum;
                int qrow = qt * 16 + lr;
                int sw = (qrow & 7) << 4;
#pragma unroll
                for (int mt = 0; mt < 4; ++mt) {
                    uint2 uv;
                    uv.x = (unsigned)f2bf(s[mt][qt][0] * inv) |
                           ((unsigned)f2bf(s[mt][qt][1] * inv) << 16);
                    uv.y = (unsigned)f2bf(s[mt][qt][2] * inv) |
                           ((unsigned)f2bf(s[mt][qt][3] * inv) << 16);
                    *(uint2*)(P + qrow * 128 + ((mt * 32 + lg * 8) ^ sw)) = uv;
                }
            }
            bf16x8 vf[2][2];
#pragma unroll
            for (int ks = 0; ks < 2; ++ks)
#pragma unroll
                for (int nt = 0; nt < 2; ++nt) {
                    int d = nt * 16 + lr;
                    vf[ks][nt] = *(const bf16x8*)(vt + d * 128 +
                        ((ks * 64 + lg * 16) ^ ((d & 7) << 4)));
                }
            f32x4 o[4][2];
#pragma unroll
            for (int mt = 0; mt < 4; ++mt) {
                o[mt][0] = zf; o[mt][1] = zf;
                int q = mt * 16 + lr;
                int sw = (q & 7) << 4;
#pragma unroll
                for (int ks = 0; ks < 2; ++ks) {
                    bf16x8 pf = *(const bf16x8*)(P + q * 128 + ((ks * 64 + lg * 16) ^ sw));
                    o[mt][0] = __builtin_amdgcn_mfma_f32_16x16x32_bf16(pf, vf[ks][0], o[mt][0], 0, 0, 0);
                    o[mt][1] = __builtin_amdgcn_mfma_f32_16x16x32_bf16(pf, vf[ks][1], o[mt][1], 0, 0, 0);
                }
            }
#pragma unroll
            for (int mt = 0; mt < 4; ++mt)
#pragma unroll
                for (int nt = 0; nt < 2; ++nt)
#pragma unroll
                    for (int r = 0; r < 4; ++r) {
                        int q = mt * 16 + 4 * lg + r;
                        if (q < 49)
                            ao[q * 512 + h * 32 + nt * 16 + lr] = f2bf(o[mt][nt][r]);
                    }
        }
        __syncthreads();
    }
}

extern "C" void kernel_launch(void* const* d_in, const int* in_sizes, int n_in,
                              void* d_out, int out_size, void* d_ws, size_t ws_size,
                              hipStream_t stream) {
    const float* x          = (const float*)d_in[0];
    const float* qkv_w      = (const float*)d_in[1];
    const float* qkv_b      = (const float*)d_in[2];
    const float* proj_w     = (const float*)d_in[3];
    const float* proj_b     = (const float*)d_in[4];
    const float* bias_table = (const float*)d_in[5];

    unsigned short* wqkv_f  = (unsigned short*)d_ws;
    unsigned short* wproj_f = wqkv_f + 786432;                 // @1.5MB
    float*          bias_f  = (float*)(wproj_f + 262144);      // @2.0MB

    if (ws_size >= WS2) {
        float* qkvb_r = (float*)((char*)d_ws + 2359296);
        unsigned short* xs      = (unsigned short*)((char*)d_ws + OFF_XS);
        unsigned short* qkv_ws  = (unsigned short*)((char*)d_ws + OFF_QKVWS);
        unsigned short* attnout = xs;   // overlay: xs dead after qkv_gemm
        hipLaunchKernelGGL(prepN_kernel, dim3(3905), dim3(256), 0, stream,
                           x, qkv_w, qkv_b, proj_w, bias_table,
                           wqkv_f, wproj_f, bias_f, qkvb_r, xs);
        hipLaunchKernelGGL(qkv_gemm_kernel, dim3(9408), dim3(256), 0, stream,
                           xs, wqkv_f, qkvb_r, qkv_ws);
        hipLaunchKernelGGL(attn2_kernel, dim3(2048), dim3(256), 0, stream,
                           qkv_ws, bias_f, attnout);
        hipLaunchKernelGGL(proj_kernel, dim3(3136), dim3(256), 0, stream,
                           attnout, wproj_f, proj_b, (float*)d_out);
    } else if (ws_size >= WS_R2) {
        unsigned short* attnout = (unsigned short*)((char*)d_ws + 2359296);
        hipLaunchKernelGGL(prep2_kernel, dim3(768), dim3(256), 0, stream,
                           qkv_w, proj_w, bias_table, wqkv_f, wproj_f, bias_f);
        hipLaunchKernelGGL(attn_qkv_kernel, dim3(2048), dim3(256), 0, stream,
                           x, qkv_b, wqkv_f, bias_f, attnout);
        hipLaunchKernelGGL(proj_kernel, dim3(3136), dim3(256), 0, stream,
                           attnout, wproj_f, proj_b, (float*)d_out);
    }
}

// Round 5
// 530.724 us; speedup vs baseline: 1.7524x; 1.1760x over previous
//
#include <hip/hip_runtime.h>

// WindowAttention for MI355X (gfx950) — round 5: fused QKV-GEMM + attention.
//  prepN:    weights->bf16 reorder (head,which,d), bias gather(-1e30 pads),
//            qkv-bias reorder, x -> bf16 PADDED pre-swizzled copy (xs[131072][512]).
//  qkvattn:  block = (2 windows, 1 head). GEMM M=128 x N=96 x K=512 with
//            global_load_lds both operands (proj-proven core), epilogue
//            scatters q/k/vt into LDS, then wave-local attention (swapped
//            QK^T + shfl softmax + wave-private P), writes compact attnout.
//  proj:     m97-style 128x128 GEMM (unchanged, proven).
// Fallback: R2 path if ws too small.

typedef __bf16 bf16x8 __attribute__((ext_vector_type(8)));
typedef float f32x4 __attribute__((ext_vector_type(4)));

#define SCALE_Q 0.17677669529663687f

// ---- ws layout (bytes), new path ----
//  [0,        1572864)    wqkv_f  bf16 [1536][512], row c = head*96+which*32+d
//  [1572864,  2097152)    wproj_f bf16 [512][512] row-major
//  [2097152,  2359296)    bias_f  f32 [16][64][64], -1e30 pads
//  [2359296,  2365440)    qkvb_r  f32 [1536] reordered (head,which,d)
//  [2365440,  136583168)  xs      bf16 [131072][512] padded, pre-swizzled
//  [136583168,239343616)  attnout bf16 [100352][512] compact
#define OFF_XS     2365440ull
#define OFF_ATTN   136583168ull
#define WS2        507779072ull
#define WS_R2      105119744ull

__device__ __forceinline__ unsigned short f2bf(float f) {
    unsigned int u = __float_as_uint(f);
    u += 0x7FFFu + ((u >> 16) & 1u);
    return (unsigned short)(u >> 16);
}

__device__ __forceinline__ uint4 pack8(const unsigned short o[8]) {
    uint4 p;
    p.x = (unsigned)o[0] | ((unsigned)o[1] << 16);
    p.y = (unsigned)o[2] | ((unsigned)o[3] << 16);
    p.z = (unsigned)o[4] | ((unsigned)o[5] << 16);
    p.w = (unsigned)o[6] | ((unsigned)o[7] << 16);
    return p;
}

union BU8 { bf16x8 v; unsigned short s[8]; };

#define GLOAD16(g, l) __builtin_amdgcn_global_load_lds( \
    (__attribute__((address_space(1))) void*)(void*)(g), \
    (__attribute__((address_space(3))) void*)(l), 16, 0, 0)

// ================= prepN =================
__global__ void prepN_kernel(const float* __restrict__ x,
                             const float* __restrict__ qkv_w,
                             const float* __restrict__ qkv_b,
                             const float* __restrict__ proj_w,
                             const float* __restrict__ bias_table,
                             unsigned short* __restrict__ wqkv_f,
                             unsigned short* __restrict__ wproj_f,
                             float* __restrict__ bias_f,
                             float* __restrict__ qkvb_r,
                             unsigned short* __restrict__ xs) {
    int b = blockIdx.x, t = threadIdx.x;
    if (b < 384) {
        // wqkv_f[c][k], c = head*96 + which*32 + d  <-  qkv_w[head*96+d*3+which]
        int gid = b * 256 + t;              // 98304 = 1536*64
        int c = gid >> 6, k8 = (gid & 63) * 8;
        int head = c / 96, rem = c - head * 96;
        int which = rem >> 5, d = rem & 31;
        const float* src = qkv_w + (size_t)(head * 96 + d * 3 + which) * 512 + k8;
        unsigned short o[8];
#pragma unroll
        for (int j = 0; j < 8; ++j) o[j] = f2bf(src[j]);
        *(uint4*)(wqkv_f + (size_t)c * 512 + k8) = pack8(o);
    } else if (b < 512) {
        int gid = (b - 384) * 256 + t;      // 32768 * 8 = 512*512
        const float* src = proj_w + (size_t)gid * 8;
        unsigned short o[8];
#pragma unroll
        for (int j = 0; j < 8; ++j) o[j] = f2bf(src[j]);
        *(uint4*)(wproj_f + (size_t)gid * 8) = pack8(o);
    } else if (b < 768) {
        int gid = (b - 512) * 256 + t;      // 65536
        int j = gid & 63; int i = (gid >> 6) & 63; int h = gid >> 12;
        float v = -1e30f;
        if (i < 49 && j < 49) {
            int ri = i / 7, ci = i % 7, rj = j / 7, cj = j % 7;
            int idx = (ri - rj + 6) * 13 + (ci - cj + 6);
            v = bias_table[idx * 16 + h];
        }
        bias_f[gid] = v;
    } else if (b == 768) {
        for (int c = t; c < 1536; c += 256) {
            int head = c / 96, rem = c - head * 96;
            int which = rem >> 5, d = rem & 31;
            qkvb_r[c] = qkv_b[head * 96 + d * 3 + which];
        }
    } else {
        // x -> bf16 PADDED [131072][512], pre-swizzled by dest row&7.
        // dest row = win*64 + tok (tok 49..63 clamp to 48).
        int gid = (b - 769) * 256 + t;      // < 1048576 = 131072*8
        int row = gid >> 3, kt = gid & 7;
        int win = row >> 6, tok = row & 63; if (tok > 48) tok = 48;
        int sw = row & 7;
        const float* src = x + ((size_t)win * 49 + tok) * 512 + kt * 64;
        unsigned short* dst = xs + (size_t)row * 512 + kt * 64;
#pragma unroll
        for (int c = 0; c < 8; ++c) {
            int cs = (c ^ sw) * 8;
            float4 a = *(const float4*)(src + cs);
            float4 bb = *(const float4*)(src + cs + 4);
            unsigned short o[8];
            o[0] = f2bf(a.x); o[1] = f2bf(a.y); o[2] = f2bf(a.z); o[3] = f2bf(a.w);
            o[4] = f2bf(bb.x); o[5] = f2bf(bb.y); o[6] = f2bf(bb.z); o[7] = f2bf(bb.w);
            *(uint4*)(dst + c * 8) = pack8(o);
        }
    }
}

// ================= K1: fused QKV GEMM + attention =================
// block = (mb: 2 windows, head). LDS:
//  [0,16384)      A stage [128][64] bf16 (swizzled)   } GEMM phase
//  [16384,28672)  B stage [96][64]  bf16 (swizzled)   }
//  [0,16384)      P: 4 waves x [32 q][64 kv] bf16     } attention (overlay)
//  [28672,53248)  qkv: 2 win x {q[64][32],k[64][32],vt[32][64]}
__global__ __launch_bounds__(256, 2)
void qkvattn_kernel(const unsigned short* __restrict__ xs,
                    const unsigned short* __restrict__ wqkv_f,
                    const float* __restrict__ qkvb_r,
                    const float* __restrict__ bias_f,
                    unsigned short* __restrict__ attnout) {
    __shared__ __align__(16) char smem[53248];
    char* As = smem;
    char* Bs = smem + 16384;

    // XCD swizzle: 16384 blocks = 8 * 2048; head-inner within an XCD.
    int i = blockIdx.x;
    int virt = (i & 7) * 2048 + (i >> 3);
    int mb = virt >> 4, head = virt & 15;
    int m0 = mb * 128;

    const int tid = threadIdx.x;
    const int l = tid & 63;
    const int W = tid >> 6;
    const int lr = l & 15;
    const int lg = l >> 4;

    f32x4 acc[2][6];
    const f32x4 zf = {0.f, 0.f, 0.f, 0.f};
#pragma unroll
    for (int mt = 0; mt < 2; ++mt)
#pragma unroll
        for (int nt = 0; nt < 6; ++nt) acc[mt][nt] = zf;

    int rsub = l >> 3, csub = l & 7;
    int cswz = (csub ^ rsub) * 16;         // B runtime inverse-swizzle
    int clin = csub * 16;                  // A linear (xs pre-swizzled)

    const char* bbase = (const char*)wqkv_f + (size_t)head * 96 * 1024;

#pragma unroll 1
    for (int kt = 0; kt < 8; ++kt) {
#pragma unroll
        for (int ii = 0; ii < 4; ++ii) {
            int r = ii * 32 + W * 8 + rsub;
            const char* srcA = (const char*)xs +
                ((size_t)(m0 + r) * 512 + kt * 64) * 2 + clin;
            GLOAD16(srcA, As + ii * 4096 + W * 1024);
        }
#pragma unroll
        for (int jj = 0; jj < 3; ++jj) {
            int r = jj * 32 + W * 8 + rsub;
            const char* srcB = bbase + ((size_t)r * 512 + kt * 64) * 2 + cswz;
            GLOAD16(srcB, Bs + jj * 4096 + W * 1024);
        }
        __syncthreads();
#pragma unroll
        for (int ks = 0; ks < 2; ++ks) {
            bf16x8 af[2], bf[6];
#pragma unroll
            for (int mt = 0; mt < 2; ++mt) {
                int row = W * 32 + mt * 16 + lr;
                af[mt] = *(const bf16x8*)(As + row * 128 +
                    ((ks * 64 + lg * 16) ^ ((row & 7) << 4)));
            }
#pragma unroll
            for (int nt = 0; nt < 6; ++nt) {
                int row = nt * 16 + lr;
                bf[nt] = *(const bf16x8*)(Bs + row * 128 +
                    ((ks * 64 + lg * 16) ^ ((row & 7) << 4)));
            }
#pragma unroll
            for (int mt = 0; mt < 2; ++mt)
#pragma unroll
                for (int nt = 0; nt < 6; ++nt)
                    acc[mt][nt] = __builtin_amdgcn_mfma_f32_16x16x32_bf16(
                        af[mt], bf[nt], acc[mt][nt], 0, 0, 0);
        }
        __syncthreads();
    }

    // ---- scatter acc -> qkv LDS ----
    // rows: W*32 + mt*16 + 4lg + r ; win_l = W>>1 ; tok = (W&1)*32 + mt*16+4lg+r
    // cols: nt*16+lr ; which = nt>>1 ; d = (nt&1)*16 + lr
    unsigned short* qkvL = (unsigned short*)(smem + 28672);
    {
        unsigned short* wbuf = qkvL + (W >> 1) * 6144;
        int tokb = (W & 1) * 32 + 4 * lg;
#pragma unroll
        for (int nt = 0; nt < 6; ++nt) {
            const int which = nt >> 1;
            const int d = (nt & 1) * 16 + lr;
            float bias = qkvb_r[head * 96 + which * 32 + d];
            float sc = (which == 0) ? SCALE_Q : 1.0f;
#pragma unroll
            for (int mt = 0; mt < 2; ++mt) {
                int tok0 = tokb + mt * 16;
#pragma unroll
                for (int r = 0; r < 4; ++r) {
                    int tok = tok0 + r;
                    float v = acc[mt][nt][r] + bias;
                    if (which == 2) {
                        // vt[d][tok], tok-chunk XOR swizzle
                        int idx = 4096 + d * 64 + (((tok >> 3) ^ (d & 7)) << 3) + (tok & 7);
                        wbuf[idx] = f2bf(v);
                    } else {
                        wbuf[which * 2048 + tok * 32 + d] = f2bf(v * sc);
                    }
                }
            }
        }
    }
    __syncthreads();

    // ---- attention: wave = (win = W>>1, q-half = W&1) ----
    {
        const unsigned short* qa = qkvL + (W >> 1) * 6144;
        char* P = smem + W * 4096;          // wave-private [32 q][64 kv] bf16
        int win_g = mb * 2 + (W >> 1);
        unsigned short* ao = attnout + (size_t)win_g * (49 * 512);

        bf16x8 qf[2], kf[4];
#pragma unroll
        for (int qt = 0; qt < 2; ++qt)
            qf[qt] = *(const bf16x8*)(qa + ((W & 1) * 32 + qt * 16 + lr) * 32 + lg * 8);
#pragma unroll
        for (int i2 = 0; i2 < 4; ++i2)
            kf[i2] = *(const bf16x8*)(qa + 2048 + (i2 * 16 + lr) * 32 + lg * 8);

        // S^T[kv][q]
        f32x4 s[4][2];
#pragma unroll
        for (int mt = 0; mt < 4; ++mt)
#pragma unroll
            for (int qt = 0; qt < 2; ++qt)
                s[mt][qt] = __builtin_amdgcn_mfma_f32_16x16x32_bf16(
                    kf[mt], qf[qt], zf, 0, 0, 0);
        // bias (kv pads = -1e30)
#pragma unroll
        for (int qt = 0; qt < 2; ++qt) {
            int q = (W & 1) * 32 + qt * 16 + lr;
            const float* bb = bias_f + ((size_t)head * 64 + q) * 64;
#pragma unroll
            for (int mt = 0; mt < 4; ++mt) {
                float4 b4 = *(const float4*)(bb + mt * 16 + lg * 4);
                s[mt][qt][0] += b4.x; s[mt][qt][1] += b4.y;
                s[mt][qt][2] += b4.z; s[mt][qt][3] += b4.w;
            }
        }
        // softmax per q column; P -> LDS bf16
#pragma unroll
        for (int qt = 0; qt < 2; ++qt) {
            float m = -1e30f;
#pragma unroll
            for (int mt = 0; mt < 4; ++mt)
#pragma unroll
                for (int r = 0; r < 4; ++r) m = fmaxf(m, s[mt][qt][r]);
            m = fmaxf(m, __shfl_xor(m, 16));
            m = fmaxf(m, __shfl_xor(m, 32));
            float sum = 0.f;
#pragma unroll
            for (int mt = 0; mt < 4; ++mt)
#pragma unroll
                for (int r = 0; r < 4; ++r) {
                    float p = __expf(s[mt][qt][r] - m);
                    s[mt][qt][r] = p; sum += p;
                }
            sum += __shfl_xor(sum, 16);
            sum += __shfl_xor(sum, 32);
            float inv = 1.0f / sum;
            int ql = qt * 16 + lr;          // 0..31 local
            int sw = (ql & 7) << 4;
#pragma unroll
            for (int mt = 0; mt < 4; ++mt) {
                uint2 uv;
                uv.x = (unsigned)f2bf(s[mt][qt][0] * inv) |
                       ((unsigned)f2bf(s[mt][qt][1] * inv) << 16);
                uv.y = (unsigned)f2bf(s[mt][qt][2] * inv) |
                       ((unsigned)f2bf(s[mt][qt][3] * inv) << 16);
                *(uint2*)(P + ql * 128 + ((mt * 32 + lg * 8) ^ sw)) = uv;
            }
        }
        // PV
        bf16x8 vf[2][2];
#pragma unroll
        for (int ks = 0; ks < 2; ++ks)
#pragma unroll
            for (int nt = 0; nt < 2; ++nt) {
                int d = nt * 16 + lr;
                vf[ks][nt] = *(const bf16x8*)(qa + 4096 + d * 64 +
                    (((ks * 4 + lg) ^ (d & 7)) << 3));
            }
        f32x4 o[2][2];
#pragma unroll
        for (int mt = 0; mt < 2; ++mt) {
            o[mt][0] = zf; o[mt][1] = zf;
            int ql = mt * 16 + lr;
            int sw = (ql & 7) << 4;
#pragma unroll
            for (int ks = 0; ks < 2; ++ks) {
                bf16x8 pf = *(const bf16x8*)(P + ql * 128 + ((ks * 64 + lg * 16) ^ sw));
                o[mt][0] = __builtin_amdgcn_mfma_f32_16x16x32_bf16(pf, vf[ks][0], o[mt][0], 0, 0, 0);
                o[mt][1] = __builtin_amdgcn_mfma_f32_16x16x32_bf16(pf, vf[ks][1], o[mt][1], 0, 0, 0);
            }
        }
#pragma unroll
        for (int mt = 0; mt < 2; ++mt)
#pragma unroll
            for (int nt = 0; nt < 2; ++nt)
#pragma unroll
                for (int r = 0; r < 4; ++r) {
                    int q = (W & 1) * 32 + mt * 16 + 4 * lg + r;
                    if (q < 49)
                        ao[q * 512 + head * 32 + nt * 16 + lr] = f2bf(o[mt][nt][r]);
                }
    }
}

// ================= K3: proj GEMM (unchanged, proven) =================
__global__ __launch_bounds__(256, 2)
void proj_kernel(const unsigned short* __restrict__ attnout,
                 const unsigned short* __restrict__ wproj_f,
                 const float* __restrict__ proj_b,
                 float* __restrict__ out) {
    __shared__ __align__(16) char smem[32768];
    char* As = smem;
    char* Bs = smem + 16384;

    int bid = blockIdx.x;
    int c = bid >> 2;
    int cs = (c & 7) * 98 + (c >> 3);
    int m0 = cs * 128;
    int n0 = (bid & 3) * 128;

    const int tid = threadIdx.x;
    const int l = tid & 63;
    const int W = tid >> 6;
    const int lr = l & 15;
    const int lg = l >> 4;
    const int Wm = W >> 1, Wn = W & 1;

    f32x4 acc[4][4];
    const f32x4 zf = {0.f, 0.f, 0.f, 0.f};
#pragma unroll
    for (int mt = 0; mt < 4; ++mt)
#pragma unroll
        for (int nt = 0; nt < 4; ++nt) acc[mt][nt] = zf;

    int rsub = l >> 3;
    int csub = l & 7;
    int cswz = (csub ^ rsub) * 16;

#pragma unroll 1
    for (int kt = 0; kt < 8; ++kt) {
#pragma unroll
        for (int i = 0; i < 4; ++i) {
            int r = i * 32 + W * 8 + rsub;
            const char* srcA = (const char*)attnout +
                ((size_t)(m0 + r) * 512 + kt * 64) * 2 + cswz;
            GLOAD16(srcA, As + i * 4096 + W * 1024);
            const char* srcB = (const char*)wproj_f +
                ((size_t)(n0 + r) * 512 + kt * 64) * 2 + cswz;
            GLOAD16(srcB, Bs + i * 4096 + W * 1024);
        }
        __syncthreads();
#pragma unroll
        for (int ks = 0; ks < 2; ++ks) {
            bf16x8 af[4], bf[4];
#pragma unroll
            for (int mt = 0; mt < 4; ++mt) {
                int row = Wm * 64 + mt * 16 + lr;
                af[mt] = *(const bf16x8*)(As + row * 128 +
                    ((ks * 64 + lg * 16) ^ ((row & 7) << 4)));
            }
#pragma unroll
            for (int nt = 0; nt < 4; ++nt) {
                int row = Wn * 64 + nt * 16 + lr;
                bf[nt] = *(const bf16x8*)(Bs + row * 128 +
                    ((ks * 64 + lg * 16) ^ ((row & 7) << 4)));
            }
#pragma unroll
            for (int mt = 0; mt < 4; ++mt)
#pragma unroll
                for (int nt = 0; nt < 4; ++nt)
                    acc[mt][nt] = __builtin_amdgcn_mfma_f32_16x16x32_bf16(
                        af[mt], bf[nt], acc[mt][nt], 0, 0, 0);
        }
        __syncthreads();
    }
#pragma unroll
    for (int nt = 0; nt < 4; ++nt) {
        int n = n0 + Wn * 64 + nt * 16 + lr;
        float pb = proj_b[n];
#pragma unroll
        for (int mt = 0; mt < 4; ++mt) {
#pragma unroll
            for (int r = 0; r < 4; ++r) {
                int m = m0 + Wm * 64 + mt * 16 + 4 * lg + r;
                out[(size_t)m * 512 + n] = acc[mt][nt][r] + pb;
            }
        }
    }
}

// =================== FALLBACK (round-2 path, proven) ===================
__global__ void prep2_kernel(const float* __restrict__ qkv_w,
                             const float* __restrict__ proj_w,
                             const float* __restrict__ bias_table,
                             unsigned short* __restrict__ wqkv_f,
                             unsigned short* __restrict__ wproj_f,
                             float* __restrict__ bias_f) {
    int b = blockIdx.x, t = threadIdx.x;
    if (b < 384) {
        int gid = b * 256 + t;
        int l = gid & 63; int r = gid >> 6;
        int dh = r & 1; r >>= 1;
        int ks = r & 15; r >>= 4;
        int h = r & 15; int which = r >> 4;
        int d = dh * 16 + (l & 15);
        int row = h * 96 + d * 3 + which;
        int c0 = ks * 32 + (l >> 4) * 8;
        const float* src = qkv_w + row * 512 + c0;
        unsigned short o[8];
#pragma unroll
        for (int j = 0; j < 8; ++j) o[j] = f2bf(src[j]);
        *(uint4*)(wqkv_f + (size_t)gid * 8) = pack8(o);
    } else if (b < 512) {
        int gid = (b - 384) * 256 + t;
        const float* src = proj_w + (size_t)gid * 8;
        unsigned short o[8];
#pragma unroll
        for (int j = 0; j < 8; ++j) o[j] = f2bf(src[j]);
        *(uint4*)(wproj_f + (size_t)gid * 8) = pack8(o);
    } else {
        int gid = (b - 512) * 256 + t;
        int j = gid & 63; int i = (gid >> 6) & 63; int h = gid >> 12;
        float v = -1e30f;
        if (i < 49 && j < 49) {
            int ri = i / 7, ci = i % 7, rj = j / 7, cj = j % 7;
            int idx = (ri - rj + 6) * 13 + (ci - cj + 6);
            v = bias_table[idx * 16 + h];
        }
        bias_f[gid] = v;
    }
}

__global__ __launch_bounds__(256, 2)
void attn_qkv_kernel(const float* __restrict__ x,
                     const float* __restrict__ qkv_b,
                     const unsigned short* __restrict__ wqkv_f,
                     const float* __restrict__ bias_f,
                     unsigned short* __restrict__ attnout) {
    __shared__ __align__(16) char smem[81920];
    const int tid = threadIdx.x;
    const int l = tid & 63;
    const int W = tid >> 6;
    const int lr = l & 15;
    const int lg = l >> 4;
    const int win = blockIdx.x;

    bf16x8 xf[16];
    {
        int trow = 16 * W + lr; if (trow > 48) trow = 48;
        const float* xr = x + ((size_t)win * 49 + trow) * 512;
#pragma unroll
        for (int ks = 0; ks < 16; ++ks) {
            float4 a = *(const float4*)(xr + ks * 32 + lg * 8);
            float4 b = *(const float4*)(xr + ks * 32 + lg * 8 + 4);
            BU8 u;
            u.s[0] = f2bf(a.x); u.s[1] = f2bf(a.y); u.s[2] = f2bf(a.z); u.s[3] = f2bf(a.w);
            u.s[4] = f2bf(b.x); u.s[5] = f2bf(b.y); u.s[6] = f2bf(b.z); u.s[7] = f2bf(b.w);
            xf[ks] = u.v;
        }
    }

    const f32x4 zf = {0.f, 0.f, 0.f, 0.f};
    unsigned short* ao = attnout + (size_t)win * (49 * 512);

    for (int hg = 0; hg < 4; ++hg) {
        for (int h2 = 0; h2 < 4; ++h2) {
            int h = hg * 4 + h2;
            char* qk = smem + h2 * 8192;
            char* vt = smem + 32768 + h2 * 4096;
#pragma unroll 1
            for (int which = 0; which < 3; ++which) {
                f32x4 a0 = zf, a1 = zf;
                const unsigned short* bp =
                    wqkv_f + (size_t)(which * 16 + h) * 16384 + l * 8;
#pragma unroll
                for (int ks = 0; ks < 16; ++ks) {
                    bf16x8 b0 = *(const bf16x8*)(bp + ks * 1024);
                    bf16x8 b1 = *(const bf16x8*)(bp + ks * 1024 + 512);
                    a0 = __builtin_amdgcn_mfma_f32_16x16x32_bf16(xf[ks], b0, a0, 0, 0, 0);
                    a1 = __builtin_amdgcn_mfma_f32_16x16x32_bf16(xf[ks], b1, a1, 0, 0, 0);
                }
                float bias0 = qkv_b[h * 96 + lr * 3 + which];
                float bias1 = qkv_b[h * 96 + (16 + lr) * 3 + which];
                if (which == 2) {
                    int d0 = lr, d1 = 16 + lr;
#pragma unroll
                    for (int r = 0; r < 4; ++r) {
                        int t = 16 * W + 4 * lg + r;
                        *(unsigned short*)(vt + d0 * 128 + ((t * 2) ^ ((d0 & 7) << 4))) =
                            f2bf(a0[r] + bias0);
                        *(unsigned short*)(vt + d1 * 128 + ((t * 2) ^ ((d1 & 7) << 4))) =
                            f2bf(a1[r] + bias1);
                    }
                } else {
                    float sc = (which == 0) ? SCALE_Q : 1.0f;
                    int cb = which * 64;
#pragma unroll
                    for (int r = 0; r < 4; ++r) {
                        int t = 16 * W + 4 * lg + r;
                        int sw = (t & 7) << 4;
                        *(unsigned short*)(qk + t * 128 + ((cb + lr * 2) ^ sw)) =
                            f2bf((a0[r] + bias0) * sc);
                        *(unsigned short*)(qk + t * 128 + ((cb + 32 + lr * 2) ^ sw)) =
                            f2bf((a1[r] + bias1) * sc);
                    }
                }
            }
        }
        __syncthreads();
        {
            int h = hg * 4 + W;
            char* qk = smem + W * 8192;
            char* vt = smem + 32768 + W * 4096;
            char* P  = smem + 49152 + W * 8192;

            bf16x8 kf[4], qf[4];
#pragma unroll
            for (int i = 0; i < 4; ++i) {
                int row = i * 16 + lr;
                int sw = (row & 7) << 4;
                qf[i] = *(const bf16x8*)(qk + row * 128 + ((lg * 16) ^ sw));
                kf[i] = *(const bf16x8*)(qk + row * 128 + ((64 + lg * 16) ^ sw));
            }
            f32x4 s[4][4];
#pragma unroll
            for (int mt = 0; mt < 4; ++mt)
#pragma unroll
                for (int qt = 0; qt < 4; ++qt)
                    s[mt][qt] = __builtin_amdgcn_mfma_f32_16x16x32_bf16(
                        kf[mt], qf[qt], zf, 0, 0, 0);
#pragma unroll
            for (int qt = 0; qt < 4; ++qt) {
                int q = qt * 16 + lr;
                const float* bb = bias_f + ((size_t)h * 64 + q) * 64;
#pragma unroll
                for (int mt = 0; mt < 4; ++mt) {
                    float4 b4 = *(const float4*)(bb + mt * 16 + lg * 4);
                    s[mt][qt][0] += b4.x; s[mt][qt][1] += b4.y;
                    s[mt][qt][2] += b4.z; s[mt][qt][3] += b4.w;
                }
            }
#pragma unroll
            for (int qt = 0; qt < 4; ++qt) {
                float m = -1e30f;
#pragma unroll
                for (int mt = 0; mt < 4; ++mt)
#pragma unroll
                    for (int r = 0; r < 4; ++r) m = fmaxf(m, s[mt][qt][r]);
                m = fmaxf(m, __shfl_xor(m, 16));
                m = fmaxf(m, __shfl_xor(m, 32));
                float sum = 0.f;
#pragma unroll
                for (int mt = 0; mt < 4; ++mt)
#pragma unroll
                    for (int r = 0; r < 4; ++r) {
                        float p = __expf(s[mt][qt][r] - m);
                        s[mt][qt][r] = p; sum += p;
                    }
                sum += __shfl_xor(sum, 16);
                sum += __shfl_xor(sum, 32);
                float inv = 1.0f / sum;
                int qrow = qt * 16 + lr;
                int sw = (qrow & 7) << 4;
#pragma unroll
                for (int mt = 0; mt < 4; ++mt) {
                    uint2 uv;
                    uv.x = (unsigned)f2bf(s[mt][qt][0] * inv) |
                           ((unsigned)f2bf(s[mt][qt][1] * inv) << 16);
                    uv.y = (unsigned)f2bf(s[mt][qt][2] * inv) |
                           ((unsigned)f2bf(s[mt][qt][3] * inv) << 16);
                    *(uint2*)(P + qrow * 128 + ((mt * 32 + lg * 8) ^ sw)) = uv;
                }
            }
            bf16x8 vf[2][2];
#pragma unroll
            for (int ks = 0; ks < 2; ++ks)
#pragma unroll
                for (int nt = 0; nt < 2; ++nt) {
                    int d = nt * 16 + lr;
                    vf[ks][nt] = *(const bf16x8*)(vt + d * 128 +
                        ((ks * 64 + lg * 16) ^ ((d & 7) << 4)));
                }
            f32x4 o[4][2];
#pragma unroll
            for (int mt = 0; mt < 4; ++mt) {
                o[mt][0] = zf; o[mt][1] = zf;
                int q = mt * 16 + lr;
                int sw = (q & 7) << 4;
#pragma unroll
                for (int ks = 0; ks < 2; ++ks) {
                    bf16x8 pf = *(const bf16x8*)(P + q * 128 + ((ks * 64 + lg * 16) ^ sw));
                    o[mt][0] = __builtin_amdgcn_mfma_f32_16x16x32_bf16(pf, vf[ks][0], o[mt][0], 0, 0, 0);
                    o[mt][1] = __builtin_amdgcn_mfma_f32_16x16x32_bf16(pf, vf[ks][1], o[mt][1], 0, 0, 0);
                }
            }
#pragma unroll
            for (int mt = 0; mt < 4; ++mt)
#pragma unroll
                for (int nt = 0; nt < 2; ++nt)
#pragma unroll
                    for (int r = 0; r < 4; ++r) {
                        int q = mt * 16 + 4 * lg + r;
                        if (q < 49)
                            ao[q * 512 + h * 32 + nt * 16 + lr] = f2bf(o[mt][nt][r]);
                    }
        }
        __syncthreads();
    }
}

extern "C" void kernel_launch(void* const* d_in, const int* in_sizes, int n_in,
                              void* d_out, int out_size, void* d_ws, size_t ws_size,
                              hipStream_t stream) {
    const float* x          = (const float*)d_in[0];
    const float* qkv_w      = (const float*)d_in[1];
    const float* qkv_b      = (const float*)d_in[2];
    const float* proj_w     = (const float*)d_in[3];
    const float* proj_b     = (const float*)d_in[4];
    const float* bias_table = (const float*)d_in[5];

    unsigned short* wqkv_f  = (unsigned short*)d_ws;
    unsigned short* wproj_f = wqkv_f + 786432;                 // @1.5MB
    float*          bias_f  = (float*)(wproj_f + 262144);      // @2.0MB

    if (ws_size >= WS2) {
        float* qkvb_r = (float*)((char*)d_ws + 2359296);
        unsigned short* xs      = (unsigned short*)((char*)d_ws + OFF_XS);
        unsigned short* attnout = (unsigned short*)((char*)d_ws + OFF_ATTN);
        hipLaunchKernelGGL(prepN_kernel, dim3(4865), dim3(256), 0, stream,
                           x, qkv_w, qkv_b, proj_w, bias_table,
                           wqkv_f, wproj_f, bias_f, qkvb_r, xs);
        hipLaunchKernelGGL(qkvattn_kernel, dim3(16384), dim3(256), 0, stream,
                           xs, wqkv_f, qkvb_r, bias_f, attnout);
        hipLaunchKernelGGL(proj_kernel, dim3(3136), dim3(256), 0, stream,
                           attnout, wproj_f, proj_b, (float*)d_out);
    } else if (ws_size >= WS_R2) {
        unsigned short* attnout = (unsigned short*)((char*)d_ws + 2359296);
        hipLaunchKernelGGL(prep2_kernel, dim3(768), dim3(256), 0, stream,
                           qkv_w, proj_w, bias_table, wqkv_f, wproj_f, bias_f);
        hipLaunchKernelGGL(attn_qkv_kernel, dim3(2048), dim3(256), 0, stream,
                           x, qkv_b, wqkv_f, bias_f, attnout);
        hipLaunchKernelGGL(proj_kernel, dim3(3136), dim3(256), 0, stream,
                           attnout, wproj_f, proj_b, (float*)d_out);
    }
}